// Round 3
// baseline (335.623 us; speedup 1.0000x reference)
//
#include <hip/hip_runtime.h>
#include <math.h>

#define VOCAB 1024
#define ED 64
#define NROWS 65536            // 64*32*32 flattened rows
#define NELEM 4194304          // 64*64*32*32
#define MARGIN 2.0e-4f         // covers bf16-approx error (worst ~2.5e-4 is 27-sigma; typ 7e-6)

typedef __attribute__((ext_vector_type(8))) short short8;
typedef __attribute__((ext_vector_type(4))) float f32x4;

__device__ __forceinline__ unsigned short f2bf(float f) {
    unsigned u = __float_as_uint(f);
    u += 0x7fff + ((u >> 16) & 1);   // RNE to bf16
    return (unsigned short)(u >> 16);
}

// ---- prep: e2f (fp64 -> fl32, proven R2 semantics) + optional bf16 codebook pack ----
__global__ void vq_prep(const float* __restrict__ emb, float* __restrict__ e2f,
                        unsigned short* __restrict__ Bbf, int use_ws) {
    int v = blockIdx.x * 256 + threadIdx.x;
    if (v >= VOCAB) return;
    float vals[ED];
    double s = 0.0;
    #pragma unroll
    for (int k4 = 0; k4 < ED / 4; ++k4) {
        float4 f = ((const float4*)(emb + v * ED))[k4];
        vals[4*k4+0] = f.x; vals[4*k4+1] = f.y; vals[4*k4+2] = f.z; vals[4*k4+3] = f.w;
    }
    #pragma unroll
    for (int k = 0; k < ED; ++k) {
        double x = (double)vals[k];
        s = fma(x, x, s);
    }
    e2f[v] = (float)s;
    if (use_ws) {
        unsigned* dst = (unsigned*)(Bbf + v * ED);
        #pragma unroll
        for (int k2 = 0; k2 < ED / 2; ++k2)
            dst[k2] = (unsigned)f2bf(vals[2*k2]) | ((unsigned)f2bf(vals[2*k2+1]) << 16);
    }
}

__global__ __launch_bounds__(256, 2)
void vq_main(const float* __restrict__ z, const float* __restrict__ emb,
             const float* __restrict__ e2f, const unsigned short* __restrict__ Bbf,
             int use_ws, float* __restrict__ out,
             double* __restrict__ loss_sum, unsigned* __restrict__ hist) {
    __shared__ float As[64 * 68];            // fp32 z rows [row][k], pad->68 (17.4 KB)
    __shared__ unsigned short Bs[128 * 80];  // bf16 codes [code_local][k], pad->80 (20.5 KB)
    __shared__ float zn_lds[64];
    __shared__ float Mb1[4 * 64];
    __shared__ int   Mi1[4 * 64];
    __shared__ float Mb2[4 * 64];
    __shared__ int   final_idx[64];
    __shared__ int   flaglist[64];
    __shared__ int   nflag;

    const int t = threadIdx.x;
    const int w = t >> 6;          // wave id: code range [w*256, w*256+256) across chunks
    const int lane = t & 63;
    const int bk = blockIdx.x;     // 1024 blocks, 64 rows each
    const int b = bk >> 4;
    const int sbase = (bk & 15) * 64;

    if (t == 0) nflag = 0;

    // ---- stage A: 64 rows x 64 k of z, fp32 ----
    {
        const int sl = t & 63, dg = t >> 6;
        #pragma unroll
        for (int i = 0; i < 16; ++i) {
            int d = dg * 16 + i;
            As[sl * 68 + d] = z[b * 65536 + d * 1024 + sbase + sl];
        }
    }
    __syncthreads();

    // ---- zn = fl32(fp64 ||z||^2) per row (R2-proven method) ----
    if (t < 64) {
        double s = 0.0;
        #pragma unroll
        for (int k = 0; k < 64; ++k) {
            double x = (double)As[t * 68 + k];
            s = fma(x, x, s);
        }
        zn_lds[t] = (float)s;
    }

    // ---- A fragments: bf16(-2*z), kept in regs for all chunks ----
    // A layout (16x16x32): lane holds A[m=lane&15][k = (lane>>4)*8 + j], j=0..7
    short8 afrag[4][2];
    {
        const int m_lo = lane & 15, q = lane >> 4;
        #pragma unroll
        for (int rt = 0; rt < 4; ++rt) {
            int m = rt * 16 + m_lo;
            #pragma unroll
            for (int kh = 0; kh < 2; ++kh) {
                const float* p = &As[m * 68 + kh * 32 + q * 8];
                float4 f0 = *(const float4*)p;
                float4 f1 = *(const float4*)(p + 4);
                short8 fr;
                fr[0] = (short)f2bf(-2.0f * f0.x);
                fr[1] = (short)f2bf(-2.0f * f0.y);
                fr[2] = (short)f2bf(-2.0f * f0.z);
                fr[3] = (short)f2bf(-2.0f * f0.w);
                fr[4] = (short)f2bf(-2.0f * f1.x);
                fr[5] = (short)f2bf(-2.0f * f1.y);
                fr[6] = (short)f2bf(-2.0f * f1.z);
                fr[7] = (short)f2bf(-2.0f * f1.w);
                afrag[rt][kh] = fr;
            }
        }
    }

    // preload e2 for this wave's code columns
    const int code_lo = w * 32 + (lane & 15);
    float e2v[8][2];
    #pragma unroll
    for (int c = 0; c < 8; ++c) {
        e2v[c][0] = e2f[c * 128 + code_lo];
        e2v[c][1] = e2f[c * 128 + code_lo + 16];
    }

    // per-slot (row) top-2 tracking: slot = rt*4+reg -> row = rt*16 + quad*4 + reg
    float b1[16], b2[16]; int i1[16];
    #pragma unroll
    for (int s = 0; s < 16; ++s) { b1[s] = 3.4e38f; b2[s] = 3.4e38f; i1[s] = 0; }

    for (int c = 0; c < 8; ++c) {
        __syncthreads();
        // ---- stage B chunk: codes [c*128, c*128+128) as bf16 ----
        {
            const int cl = t >> 1, half = t & 1;
            const int code = c * 128 + cl;
            if (use_ws) {
                const uint4* src = (const uint4*)(Bbf + code * 64 + half * 32);
                uint4* dst = (uint4*)(Bs + cl * 80 + half * 32);
                #pragma unroll
                for (int j = 0; j < 4; ++j) dst[j] = src[j];
            } else {
                const float4* src = (const float4*)(emb + code * 64 + half * 32);
                unsigned* dst = (unsigned*)(Bs + cl * 80 + half * 32);
                #pragma unroll
                for (int j = 0; j < 8; ++j) {
                    float4 f = src[j];
                    dst[j*2+0] = (unsigned)f2bf(f.x) | ((unsigned)f2bf(f.y) << 16);
                    dst[j*2+1] = (unsigned)f2bf(f.z) | ((unsigned)f2bf(f.w) << 16);
                }
            }
        }
        __syncthreads();

        // ---- B fragments: B[n=lane&15][k=(lane>>4)*8+j] from emb-layout [n][k] ----
        short8 bfrag[2][2];
        {
            const int q = lane >> 4, n_lo = lane & 15;
            #pragma unroll
            for (int ct = 0; ct < 2; ++ct) {
                int cl = w * 32 + ct * 16 + n_lo;
                #pragma unroll
                for (int kh = 0; kh < 2; ++kh)
                    bfrag[ct][kh] = *(const short8*)(Bs + cl * 80 + kh * 32 + q * 8);
            }
        }

        // ---- MFMA: D = e2f[c] + (-2z)·e ----
        f32x4 acc[4][2];
        #pragma unroll
        for (int rt = 0; rt < 4; ++rt) {
            #pragma unroll
            for (int ct = 0; ct < 2; ++ct) {
                f32x4 a;
                a[0] = e2v[c][ct]; a[1] = e2v[c][ct]; a[2] = e2v[c][ct]; a[3] = e2v[c][ct];
                a = __builtin_amdgcn_mfma_f32_16x16x32_bf16(afrag[rt][0], bfrag[ct][0], a, 0, 0, 0);
                a = __builtin_amdgcn_mfma_f32_16x16x32_bf16(afrag[rt][1], bfrag[ct][1], a, 0, 0, 0);
                acc[rt][ct] = a;
            }
        }

        // ---- scoring: top-2 per slot ----
        #pragma unroll
        for (int rt = 0; rt < 4; ++rt) {
            #pragma unroll
            for (int reg = 0; reg < 4; ++reg) {
                const int slot = rt * 4 + reg;
                #pragma unroll
                for (int ct = 0; ct < 2; ++ct) {
                    float s = acc[rt][ct][reg];
                    int code = c * 128 + code_lo + ct * 16;
                    float mn = fminf(s, b2[slot]);
                    bool lt = s < b1[slot];
                    b2[slot] = lt ? b1[slot] : mn;
                    i1[slot] = lt ? code : i1[slot];
                    b1[slot] = lt ? s : b1[slot];
                }
            }
        }
    }

    // ---- butterfly merge across the 16 lanes of each quad ----
    #pragma unroll
    for (int m = 1; m < 16; m <<= 1) {
        #pragma unroll
        for (int s = 0; s < 16; ++s) {
            float ob1 = __shfl_xor(b1[s], m, 64);
            int   oi1 = __shfl_xor(i1[s], m, 64);
            float ob2 = __shfl_xor(b2[s], m, 64);
            float lose = fmaxf(b1[s], ob1);
            b2[s] = fminf(fminf(b2[s], ob2), lose);
            bool take = (ob1 < b1[s]) || (ob1 == b1[s] && oi1 < i1[s]);
            b1[s] = take ? ob1 : b1[s];
            i1[s] = take ? oi1 : i1[s];
        }
    }
    if ((lane & 15) == 0) {
        const int q = lane >> 4;
        #pragma unroll
        for (int rt = 0; rt < 4; ++rt) {
            #pragma unroll
            for (int reg = 0; reg < 4; ++reg) {
                int row = rt * 16 + q * 4 + reg;
                int s = rt * 4 + reg;
                Mb1[w * 64 + row] = b1[s];
                Mi1[w * 64 + row] = i1[s];
                Mb2[w * 64 + row] = b2[s];
            }
        }
    }
    __syncthreads();

    // ---- per-row merge of 4 waves; flag rows with 2nd-best within margin ----
    if (t < 64) {
        float B1 = Mb1[t]; int I1 = Mi1[t]; float B2 = Mb2[t];
        #pragma unroll
        for (int ww = 1; ww < 4; ++ww) {
            float ob1 = Mb1[ww * 64 + t]; int oi1 = Mi1[ww * 64 + t]; float ob2 = Mb2[ww * 64 + t];
            float lose = fmaxf(B1, ob1);
            B2 = fminf(fminf(B2, ob2), lose);
            if (ob1 < B1 || (ob1 == B1 && oi1 < I1)) { B1 = ob1; I1 = oi1; }
        }
        final_idx[t] = I1;
        if (B2 < B1 + MARGIN) {
            int p = atomicAdd(&nflag, 1);
            flaglist[p] = t;
        }
    }
    __syncthreads();

    // ---- exact rescue (R2-proven fp32 semantics), one wave per flagged row ----
    const int nf = nflag;
    for (int fi = w; fi < nf; fi += 4) {
        const int row = flaglist[fi];
        float zr[64];
        #pragma unroll
        for (int k4 = 0; k4 < 16; ++k4) {
            float4 f = *(const float4*)&As[row * 68 + k4 * 4];
            zr[4*k4+0] = f.x; zr[4*k4+1] = f.y; zr[4*k4+2] = f.z; zr[4*k4+3] = f.w;
        }
        const float znr = zn_lds[row];
        float bv = 3.4e38f; int bi = 0;
        #pragma unroll 1
        for (int g = 0; g < 4; ++g) {
            const int c0 = lane * 16 + g * 4;
            const float* p0 = emb + (c0 + 0) * 64;
            const float* p1 = emb + (c0 + 1) * 64;
            const float* p2 = emb + (c0 + 2) * 64;
            const float* p3 = emb + (c0 + 3) * 64;
            float m0 = 0.f, m1 = 0.f, m2 = 0.f, m3 = 0.f;
            #pragma unroll
            for (int k = 0; k < 64; k += 4) {
                float4 e0 = *(const float4*)(p0 + k);
                float4 e1 = *(const float4*)(p1 + k);
                float4 e2_ = *(const float4*)(p2 + k);
                float4 e3 = *(const float4*)(p3 + k);
                m0 = fmaf(zr[k], e0.x, m0);  m0 = fmaf(zr[k+1], e0.y, m0);
                m0 = fmaf(zr[k+2], e0.z, m0); m0 = fmaf(zr[k+3], e0.w, m0);
                m1 = fmaf(zr[k], e1.x, m1);  m1 = fmaf(zr[k+1], e1.y, m1);
                m1 = fmaf(zr[k+2], e1.z, m1); m1 = fmaf(zr[k+3], e1.w, m1);
                m2 = fmaf(zr[k], e2_.x, m2); m2 = fmaf(zr[k+1], e2_.y, m2);
                m2 = fmaf(zr[k+2], e2_.z, m2); m2 = fmaf(zr[k+3], e2_.w, m2);
                m3 = fmaf(zr[k], e3.x, m3);  m3 = fmaf(zr[k+1], e3.y, m3);
                m3 = fmaf(zr[k+2], e3.z, m3); m3 = fmaf(zr[k+3], e3.w, m3);
            }
            float tt, d;
            tt = znr + e2f[c0+0]; d = tt - 2.0f * m0; if (d < bv) { bv = d; bi = c0 + 0; }
            tt = znr + e2f[c0+1]; d = tt - 2.0f * m1; if (d < bv) { bv = d; bi = c0 + 1; }
            tt = znr + e2f[c0+2]; d = tt - 2.0f * m2; if (d < bv) { bv = d; bi = c0 + 2; }
            tt = znr + e2f[c0+3]; d = tt - 2.0f * m3; if (d < bv) { bv = d; bi = c0 + 3; }
        }
        #pragma unroll
        for (int m = 1; m < 64; m <<= 1) {
            float obv = __shfl_xor(bv, m, 64);
            int   obi = __shfl_xor(bi, m, 64);
            if (obv < bv || (obv == bv && obi < bi)) { bv = obv; bi = obi; }
        }
        if (lane == 0) final_idx[row] = bi;
    }
    __syncthreads();

    // ---- epilogue: indices, hist, z_q_st, loss ----
    {
        const int r = t & 63, dg = t >> 6;
        const int code = final_idx[r];
        if (t < 64) {
            out[NELEM + bk * 64 + r] = (float)code;
            atomicAdd(&hist[code], 1u);
        }
        double lsum = 0.0;
        const float4* ep = (const float4*)(emb + code * 64);
        #pragma unroll
        for (int i = 0; i < 4; ++i) {
            float4 ev = ep[dg * 4 + i];
            float4 zf = *(const float4*)&As[r * 68 + dg * 16 + i * 4];
            float zs[4] = {zf.x, zf.y, zf.z, zf.w};
            float es[4] = {ev.x, ev.y, ev.z, ev.w};
            #pragma unroll
            for (int cc = 0; cc < 4; ++cc) {
                int d = dg * 16 + i * 4 + cc;
                out[b * 65536 + d * 1024 + sbase + r] = zs[cc] + (es[cc] - zs[cc]);
                double df = (double)es[cc] - (double)zs[cc];
                lsum = fma(df, df, lsum);
            }
        }
        #pragma unroll
        for (int off = 32; off > 0; off >>= 1)
            lsum += __shfl_down(lsum, off, 64);
        if (lane == 0) atomicAdd(loss_sum, lsum);
    }
}

__global__ void vq_finalize_kernel(const unsigned* __restrict__ hist,
                                   const double* __restrict__ loss_sum,
                                   float* __restrict__ out) {
    __shared__ double red[256];
    int t = threadIdx.x;
    double ssum = 0.0;
    for (int i = t; i < VOCAB; i += 256) {
        double p = (double)hist[i] / (double)NROWS;
        ssum += p * log(p + 1e-10);
    }
    red[t] = ssum;
    __syncthreads();
    for (int off = 128; off > 0; off >>= 1) {
        if (t < off) red[t] += red[t + off];
        __syncthreads();
    }
    if (t == 0) {
        double qv = loss_sum[0] / (double)NELEM;
        out[NELEM + NROWS + 0] = (float)qv;
        out[NELEM + NROWS + 1] = (float)(qv * 0.25);
        out[NELEM + NROWS + 2] = (float)exp(-red[0]);
    }
}

extern "C" void kernel_launch(void* const* d_in, const int* in_sizes, int n_in,
                              void* d_out, int out_size, void* d_ws, size_t ws_size,
                              hipStream_t stream) {
    const float* z   = (const float*)d_in[0];
    const float* emb = (const float*)d_in[1];
    float* out = (float*)d_out;

    const size_t NEED_WS = 4096 + 131072 + 8 + 4096;
    const int use_ws = (ws_size >= NEED_WS) ? 1 : 0;

    float* e2f = (float*)d_ws;
    unsigned short* Bbf;
    double* loss;
    unsigned* hist;
    if (use_ws) {
        Bbf  = (unsigned short*)((char*)d_ws + 4096);
        loss = (double*)((char*)d_ws + 4096 + 131072);
        hist = (unsigned*)((char*)d_ws + 4096 + 131072 + 8);
        hipMemsetAsync((char*)d_ws + 4096 + 131072, 0, 8 + 4096, stream);
    } else {
        Bbf  = nullptr;
        loss = (double*)((char*)d_ws + 4096);
        hist = (unsigned*)((char*)d_ws + 4104);
        hipMemsetAsync((char*)d_ws + 4096, 0, 8 + 4096, stream);
    }

    vq_prep<<<dim3(4), dim3(256), 0, stream>>>(emb, e2f, Bbf, use_ws);
    vq_main<<<dim3(1024), dim3(256), 0, stream>>>(z, emb, e2f, Bbf, use_ws, out, loss, hist);
    vq_finalize_kernel<<<dim3(1), dim3(256), 0, stream>>>(hist, loss, out);
}

// Round 4
// 261.410 us; speedup vs baseline: 1.2839x; 1.2839x over previous
//
#include <hip/hip_runtime.h>
#include <math.h>

#define VOCAB 1024
#define ED 64
#define NROWS 65536            // 64*32*32 flattened rows
#define NELEM 4194304          // 64*64*32*32
#define MARGIN 2.0e-4f         // validated in R3 (passed with absmax 0)
#define CAPF 16384             // flag-list capacity (expect ~2600 flags)

typedef __attribute__((ext_vector_type(8))) short short8;
typedef __attribute__((ext_vector_type(4))) float f32x4;

__device__ __forceinline__ unsigned short f2bf(float f) {
    unsigned u = __float_as_uint(f);
    u += 0x7fff + ((u >> 16) & 1);   // RNE to bf16
    return (unsigned short)(u >> 16);
}

// ws layout:
//   [0,      4096)   float  e2f[1024]          fl32(fp64 ||e||^2)  (R2-proven)
//   [4096,   135168) ushort Bf[8192*8]         bf16 codebook, MFMA-fragment order
//   [135168, 135176) double loss_sum
//   [135176, 135180) unsigned nflag
//   [135184, 139280) unsigned hist[1024]
//   [139280, 204816) unsigned flaglist[16384]

// ---------------- prep: e2f + fragment-ordered bf16 codebook ----------------
__global__ void vq_prep(const float* __restrict__ emb, float* __restrict__ e2f,
                        unsigned short* __restrict__ Bf) {
    int v = blockIdx.x * 256 + threadIdx.x;
    if (v >= VOCAB) return;
    float vals[ED];
    const float4* src = (const float4*)(emb + v * ED);
    #pragma unroll
    for (int g = 0; g < 16; ++g) {
        float4 f = src[g];
        vals[4*g] = f.x; vals[4*g+1] = f.y; vals[4*g+2] = f.z; vals[4*g+3] = f.w;
    }
    double s = 0.0;
    #pragma unroll
    for (int k = 0; k < ED; ++k) { double x = (double)vals[k]; s = fma(x, x, s); }
    e2f[v] = (float)s;
    // fragment order: B[n=lane&15][k=(lane>>4)*8+j]; chunk=256 codes, tile=32
    const int c = v >> 8, t16 = (v >> 5) & 7, ct = (v >> 4) & 1, n = v & 15;
    #pragma unroll
    for (int k8 = 0; k8 < 8; ++k8) {
        const int kh = k8 >> 2, q = k8 & 3, lane = q * 16 + n;
        unsigned tmp[8];
        #pragma unroll
        for (int j = 0; j < 8; ++j) tmp[j] = (unsigned)f2bf(vals[k8 * 8 + j]);
        uint4 pk;
        pk.x = tmp[0] | (tmp[1] << 16); pk.y = tmp[2] | (tmp[3] << 16);
        pk.z = tmp[4] | (tmp[5] << 16); pk.w = tmp[6] | (tmp[7] << 16);
        ((uint4*)Bf)[(((c * 8 + t16) * 2 + ct) * 2 + kh) * 64 + lane] = pk;
    }
}

// ---------------- filter: MFMA top-2 + flag; epilogue for unflagged ----------
__global__ __launch_bounds__(128, 1)
void vq_filter(const float* __restrict__ z, const float* __restrict__ emb,
               const float* __restrict__ e2f, const unsigned short* __restrict__ Bf,
               float* __restrict__ out, double* __restrict__ loss_sum,
               unsigned* __restrict__ hist, unsigned* __restrict__ nflag,
               unsigned* __restrict__ flaglist) {
    __shared__ unsigned short Bs[2048 * 8];   // 32 KB fragment chunk (256 codes)
    __shared__ float e2s[1024];
    __shared__ float rowb1[128], rowb2[128];
    __shared__ int   rowi1[128];

    const int t = threadIdx.x;
    const int w = t >> 6, lane = t & 63;
    const int q = lane >> 4, n_lo = lane & 15;
    const int bk = blockIdx.x;        // 512 blocks, 128 rows each
    const int n0 = bk * 128;
    const int b  = n0 >> 10;
    const int sb = n0 & 1023;

    // e2 -> LDS (visible after first chunk barrier)
    #pragma unroll
    for (int i = 0; i < 8; ++i) e2s[i * 128 + t] = e2f[i * 128 + t];

    // A fragments: bf16(-2 z) for this wave's 64 rows, built once from global
    short8 af[4][2];
    #pragma unroll
    for (int rt = 0; rt < 4; ++rt) {
        const int s = sb + w * 64 + rt * 16 + n_lo;
        const float* zp = z + (size_t)b * 65536 + s;
        #pragma unroll
        for (int kh = 0; kh < 2; ++kh) {
            short8 fr;
            #pragma unroll
            for (int j = 0; j < 8; ++j) {
                int d = kh * 32 + q * 8 + j;
                fr[j] = (short)f2bf(-2.0f * zp[d * 1024]);
            }
            af[rt][kh] = fr;
        }
    }

    // per-slot top-2: slot=rt*4+reg -> row = rt*16 + q*4 + reg
    float b1[16], b2[16]; int i1[16];
    #pragma unroll
    for (int sl = 0; sl < 16; ++sl) { b1[sl] = 3.4e38f; b2[sl] = 3.4e38f; i1[sl] = 0; }

    for (int c = 0; c < 4; ++c) {
        __syncthreads();
        {   // identity-copy staging: coalesced global, stride-1 LDS
            const uint4* src = (const uint4*)Bf + c * 2048;
            uint4* dst = (uint4*)Bs;
            #pragma unroll
            for (int i = 0; i < 16; ++i) dst[i * 128 + t] = src[i * 128 + t];
        }
        __syncthreads();

        #pragma unroll
        for (int t16 = 0; t16 < 8; ++t16) {
            short8 bf0[2], bf1[2];
            #pragma unroll
            for (int kh = 0; kh < 2; ++kh) {
                bf0[kh] = ((const short8*)Bs)[((t16 * 2 + 0) * 2 + kh) * 64 + lane];
                bf1[kh] = ((const short8*)Bs)[((t16 * 2 + 1) * 2 + kh) * 64 + lane];
            }
            const int cb0 = c * 256 + t16 * 32 + n_lo;
            const float e20 = e2s[cb0], e21 = e2s[cb0 + 16];
            #pragma unroll
            for (int rt = 0; rt < 4; ++rt) {
                f32x4 a0; a0[0] = e20; a0[1] = e20; a0[2] = e20; a0[3] = e20;
                a0 = __builtin_amdgcn_mfma_f32_16x16x32_bf16(af[rt][0], bf0[0], a0, 0, 0, 0);
                a0 = __builtin_amdgcn_mfma_f32_16x16x32_bf16(af[rt][1], bf0[1], a0, 0, 0, 0);
                f32x4 a1; a1[0] = e21; a1[1] = e21; a1[2] = e21; a1[3] = e21;
                a1 = __builtin_amdgcn_mfma_f32_16x16x32_bf16(af[rt][0], bf1[0], a1, 0, 0, 0);
                a1 = __builtin_amdgcn_mfma_f32_16x16x32_bf16(af[rt][1], bf1[1], a1, 0, 0, 0);
                #pragma unroll
                for (int reg = 0; reg < 4; ++reg) {
                    const int sl = rt * 4 + reg;
                    float s0 = a0[reg];
                    b2[sl] = __builtin_amdgcn_fmed3f(s0, b1[sl], b2[sl]);
                    bool lt0 = s0 < b1[sl];
                    i1[sl] = lt0 ? cb0 : i1[sl];
                    b1[sl] = lt0 ? s0 : b1[sl];
                    float s1 = a1[reg];
                    b2[sl] = __builtin_amdgcn_fmed3f(s1, b1[sl], b2[sl]);
                    bool lt1 = s1 < b1[sl];
                    i1[sl] = lt1 ? (cb0 + 16) : i1[sl];
                    b1[sl] = lt1 ? s1 : b1[sl];
                }
            }
        }
    }

    // merge across the 16 code-lanes of each quad (xor over lane bits 0..3)
    #pragma unroll
    for (int m = 1; m < 16; m <<= 1) {
        #pragma unroll
        for (int sl = 0; sl < 16; ++sl) {
            float ob1 = __shfl_xor(b1[sl], m, 64);
            int   oi1 = __shfl_xor(i1[sl], m, 64);
            float ob2 = __shfl_xor(b2[sl], m, 64);
            float lose = fmaxf(b1[sl], ob1);
            b2[sl] = fminf(fminf(b2[sl], ob2), lose);
            bool take = (ob1 < b1[sl]) || (ob1 == b1[sl] && oi1 < i1[sl]);
            b1[sl] = take ? ob1 : b1[sl];
            i1[sl] = take ? oi1 : i1[sl];
        }
    }
    if (n_lo == 0) {
        #pragma unroll
        for (int rt = 0; rt < 4; ++rt) {
            #pragma unroll
            for (int reg = 0; reg < 4; ++reg) {
                int row = rt * 16 + q * 4 + reg;
                int sl = rt * 4 + reg;
                rowb1[w * 64 + row] = b1[sl];
                rowb2[w * 64 + row] = b2[sl];
                rowi1[w * 64 + row] = i1[sl];
            }
        }
    }
    __syncthreads();

    // epilogue: one thread per row
    {
        const int r = t;
        const int nrow = n0 + r;
        const int s = sb + r;
        const int code = rowi1[r];
        bool flagged = rowb2[r] < rowb1[r] + MARGIN;
        if (flagged) {
            unsigned p = atomicAdd(nflag, 1u);
            if (p < CAPF) flaglist[p] = (unsigned)nrow;
            else flagged = false;   // overflow: keep filter result (never hit in practice)
        }
        out[NELEM + nrow] = (float)code;     // rescue overwrites if flagged
        if (!flagged) atomicAdd(&hist[code], 1u);
        const float4* ep = (const float4*)(emb + code * ED);
        const float* zp = z + (size_t)b * 65536 + s;
        float* op = out + (size_t)b * 65536 + s;
        double lsum = 0.0;
        #pragma unroll
        for (int g = 0; g < 16; ++g) {
            float4 ev = ep[g];
            float es[4] = {ev.x, ev.y, ev.z, ev.w};
            #pragma unroll
            for (int cc = 0; cc < 4; ++cc) {
                int d = g * 4 + cc;
                float zv = zp[d * 1024];
                op[d * 1024] = zv + (es[cc] - zv);
                double df = (double)es[cc] - (double)zv;
                lsum = fma(df, df, lsum);
            }
        }
        if (flagged) lsum = 0.0;             // rescue adds flagged rows' loss
        #pragma unroll
        for (int off = 32; off > 0; off >>= 1)
            lsum += __shfl_down(lsum, off, 64);
        if (lane == 0) atomicAdd(loss_sum, lsum);
    }
}

// ---------------- rescue: exact R2 semantics for flagged rows ----------------
__global__ __launch_bounds__(256, 1)
void vq_rescue(const float* __restrict__ z, const float* __restrict__ emb,
               const float* __restrict__ e2f, float* __restrict__ out,
               double* __restrict__ loss_sum, unsigned* __restrict__ hist,
               const unsigned* __restrict__ nflag,
               const unsigned* __restrict__ flaglist) {
    __shared__ float ec[128 * 64];     // 32 KB fp32 code chunk, float4-XOR-swizzled
    __shared__ float zrows[64 * 64];   // 16 KB: 4 waves x up to 16 rows
    __shared__ float s_zn[64], s_bv[64];
    __shared__ int   s_bi[64], s_rid[64];

    const int t = threadIdx.x, w = t >> 6, lane = t & 63;
    const int bid = blockIdx.x;
    unsigned nfr = *nflag;
    const int nf = (int)(nfr < CAPF ? nfr : CAPF);
    if (nf <= bid * 4) return;         // block-uniform early exit (before barriers)
    const int gw = bid * 4 + w;

    // load this wave's rows (<=16): z, zn (fp64 butterfly -> fl32), init state
    int mr = 0;
    for (int fi = gw; fi < nf && mr < 16; fi += 1024) {
        int n = (int)flaglist[fi];
        int bb = n >> 10, s = n & 1023;
        float v = z[(size_t)bb * 65536 + (size_t)lane * 1024 + s];
        zrows[(w * 16 + mr) * 64 + lane] = v;
        double sq = (double)v * (double)v;
        #pragma unroll
        for (int off = 32; off > 0; off >>= 1) sq += __shfl_xor(sq, off, 64);
        if (lane == 0) {
            s_rid[w * 16 + mr] = n;
            s_zn[w * 16 + mr] = (float)sq;
            s_bv[w * 16 + mr] = 3.4e38f;
            s_bi[w * 16 + mr] = 0;
        }
        ++mr;
    }

    for (int c = 0; c < 8; ++c) {
        __syncthreads();
        {   // stage 128 codes fp32, swizzle float4 index by (code&15)
            const int cl = t >> 1, h = t & 1;
            const float4* src = (const float4*)(emb + (c * 128 + cl) * 64 + h * 32);
            #pragma unroll
            for (int jj = 0; jj < 8; ++jj) {
                int k4 = h * 8 + jj;
                *(float4*)&ec[cl * 64 + ((k4 ^ (cl & 15)) * 4)] = src[jj];
            }
        }
        __syncthreads();
        for (int j = 0; j < mr; ++j) {
            const float* zr = &zrows[(w * 16 + j) * 64];
            const int c0 = c * 128 + lane, c1 = c0 + 64;
            const int sw = lane & 15;
            float m0 = 0.f, m1 = 0.f;
            #pragma unroll
            for (int k4 = 0; k4 < 16; ++k4) {
                float4 zq = *(const float4*)&zr[k4 * 4];
                float4 e0 = *(const float4*)&ec[lane * 64 + ((k4 ^ sw) * 4)];
                float4 e1 = *(const float4*)&ec[(lane + 64) * 64 + ((k4 ^ sw) * 4)];
                m0 = fmaf(zq.x, e0.x, m0); m0 = fmaf(zq.y, e0.y, m0);
                m0 = fmaf(zq.z, e0.z, m0); m0 = fmaf(zq.w, e0.w, m0);
                m1 = fmaf(zq.x, e1.x, m1); m1 = fmaf(zq.y, e1.y, m1);
                m1 = fmaf(zq.z, e1.z, m1); m1 = fmaf(zq.w, e1.w, m1);
            }
            const float znj = s_zn[w * 16 + j];
            float tt0 = znj + e2f[c0]; float d0 = tt0 - 2.0f * m0;
            float tt1 = znj + e2f[c1]; float d1 = tt1 - 2.0f * m1;
            float dm; int cm;
            if (d1 < d0) { dm = d1; cm = c1; } else { dm = d0; cm = c0; }
            #pragma unroll
            for (int off = 1; off < 64; off <<= 1) {
                float od = __shfl_xor(dm, off, 64);
                int   oc = __shfl_xor(cm, off, 64);
                if (od < dm || (od == dm && oc < cm)) { dm = od; cm = oc; }
            }
            if (lane == 0) {
                int ix = w * 16 + j;
                if (dm < s_bv[ix] || (dm == s_bv[ix] && cm < s_bi[ix])) {
                    s_bv[ix] = dm; s_bi[ix] = cm;
                }
            }
        }
    }

    // epilogue per row: index, hist, z_q_st, loss
    for (int j = 0; j < mr; ++j) {
        int n = s_rid[w * 16 + j];
        int bb = n >> 10, s = n & 1023;
        int code = s_bi[w * 16 + j];
        float zvv = zrows[(w * 16 + j) * 64 + lane];
        float e = emb[code * 64 + lane];
        out[(size_t)bb * 65536 + (size_t)lane * 1024 + s] = zvv + (e - zvv);
        double df = (double)e - (double)zvv;
        double ls = df * df;
        #pragma unroll
        for (int off = 32; off > 0; off >>= 1) ls += __shfl_xor(ls, off, 64);
        if (lane == 0) {
            out[NELEM + n] = (float)code;
            atomicAdd(&hist[code], 1u);
            atomicAdd(loss_sum, ls);
        }
    }
}

// ---------------- finalize ----------------
__global__ void vq_finalize_kernel(const unsigned* __restrict__ hist,
                                   const double* __restrict__ loss_sum,
                                   float* __restrict__ out) {
    __shared__ double red[256];
    int t = threadIdx.x;
    double ssum = 0.0;
    for (int i = t; i < VOCAB; i += 256) {
        double p = (double)hist[i] / (double)NROWS;
        ssum += p * log(p + 1e-10);
    }
    red[t] = ssum;
    __syncthreads();
    for (int off = 128; off > 0; off >>= 1) {
        if (t < off) red[t] += red[t + off];
        __syncthreads();
    }
    if (t == 0) {
        double qv = loss_sum[0] / (double)NELEM;
        out[NELEM + NROWS + 0] = (float)qv;
        out[NELEM + NROWS + 1] = (float)(qv * 0.25);
        out[NELEM + NROWS + 2] = (float)exp(-red[0]);
    }
}

extern "C" void kernel_launch(void* const* d_in, const int* in_sizes, int n_in,
                              void* d_out, int out_size, void* d_ws, size_t ws_size,
                              hipStream_t stream) {
    const float* z   = (const float*)d_in[0];   // (64,64,32,32) fp32
    const float* emb = (const float*)d_in[1];   // (1024,64) fp32
    float* out = (float*)d_out;

    float*          e2f  = (float*)d_ws;
    unsigned short* Bf   = (unsigned short*)((char*)d_ws + 4096);
    double*         loss = (double*)((char*)d_ws + 135168);
    unsigned*       nfl  = (unsigned*)((char*)d_ws + 135176);
    unsigned*       hist = (unsigned*)((char*)d_ws + 135184);
    unsigned*       flg  = (unsigned*)((char*)d_ws + 139280);

    // zero loss_sum + nflag + hist (ws is re-poisoned 0xAA before timed calls)
    hipMemsetAsync((char*)d_ws + 135168, 0, 4112, stream);

    vq_prep<<<dim3(4), dim3(256), 0, stream>>>(emb, e2f, Bf);
    vq_filter<<<dim3(512), dim3(128), 0, stream>>>(z, emb, e2f, Bf, out, loss,
                                                   hist, nfl, flg);
    vq_rescue<<<dim3(256), dim3(256), 0, stream>>>(z, emb, e2f, out, loss,
                                                   hist, nfl, flg);
    vq_finalize_kernel<<<dim3(1), dim3(256), 0, stream>>>(hist, loss, out);
}

// Round 5
// 213.676 us; speedup vs baseline: 1.5707x; 1.2234x over previous
//
#include <hip/hip_runtime.h>
#include <math.h>

#define VOCAB 1024
#define ED 64
#define NROWS 65536            // 64*32*32 flattened rows
#define NELEM 4194304          // 64*64*32*32
#define MARGIN 2.0e-4f         // validated R3/R4 (passed, absmax 0)
#define CAPF 8192              // flagged-row slots (expect ~2500-4200)
#define MAXC 6                 // candidate codes kept per flagged row

typedef __attribute__((ext_vector_type(8))) short short8;
typedef __attribute__((ext_vector_type(4))) float f32x4;

__device__ __forceinline__ unsigned f2bf(float f) {
    unsigned u = __float_as_uint(f);
    u += 0x7fff + ((u >> 16) & 1);   // RNE to bf16
    return u >> 16;
}

// ws layout:
//   [0,     4096)  float e2f[1024]     fl32(fp64 ||e||^2)  (R2-proven)
//   [4096,  4104)  double loss_sum
//   [4104,  4108)  unsigned nflag
//   [4108,  4112)  pad
//   [4112,  8208)  unsigned hist[1024]
//   [8208,  40976) unsigned rowcnt[CAPF]      (row<<12 | append_count)
//   [40976, 139280) ushort codes6[CAPF*6]     candidate codes per slot

// ---------------- prep: e2f only ----------------
__global__ void vq_prep(const float* __restrict__ emb, float* __restrict__ e2f) {
    int v = blockIdx.x * 256 + threadIdx.x;
    if (v >= VOCAB) return;
    const float4* src = (const float4*)(emb + v * ED);
    double s = 0.0;
    #pragma unroll
    for (int g = 0; g < 16; ++g) {
        float4 f = src[g];
        s = fma((double)f.x, (double)f.x, s);
        s = fma((double)f.y, (double)f.y, s);
        s = fma((double)f.z, (double)f.z, s);
        s = fma((double)f.w, (double)f.w, s);
    }
    e2f[v] = (float)s;
}

// stage chunk c (256 codes) of emb as bf16 MFMA-B fragments into Bs.
// Global reads: 32B/lane, fully coalesced (union of lane addrs contiguous).
__device__ __forceinline__ void stage_chunk(unsigned short* Bs,
                                            const float* __restrict__ emb,
                                            int c, int t) {
    const int q = t & 3, kh = (t >> 2) & 1, n = (t >> 3) & 15;
    const int L = q * 16 + n;           // fragment lane
    const int k0 = kh * 32 + q * 8;
    #pragma unroll
    for (int t16 = 0; t16 < 8; ++t16) {
        #pragma unroll
        for (int ct = 0; ct < 2; ++ct) {
            const int code = c * 256 + t16 * 32 + ct * 16 + n;
            const float4* sp = (const float4*)(emb + code * 64 + k0);
            float4 f0 = sp[0], f1 = sp[1];
            uint4 pk;
            pk.x = f2bf(f0.x) | (f2bf(f0.y) << 16);
            pk.y = f2bf(f0.z) | (f2bf(f0.w) << 16);
            pk.z = f2bf(f1.x) | (f2bf(f1.y) << 16);
            pk.w = f2bf(f1.z) | (f2bf(f1.w) << 16);
            ((uint4*)Bs)[t16 * 256 + ct * 128 + kh * 64 + L] = pk;
        }
    }
}

// ---------------- filter ----------------
__global__ __launch_bounds__(128, 1)
void vq_filter(const float* __restrict__ z, const float* __restrict__ emb,
               const float* __restrict__ e2f, float* __restrict__ out,
               double* __restrict__ loss_sum, unsigned* __restrict__ hist,
               unsigned* __restrict__ nflag, unsigned* __restrict__ rowcnt,
               unsigned short* __restrict__ codes6) {
    __shared__ unsigned short Bs[2048 * 8];   // 32 KB bf16 fragment chunk
    __shared__ float e2s[1024];
    __shared__ float rowb1[128], rowb2[128];
    __shared__ int   rowi1[128], rowslot[128];

    const int t = threadIdx.x;
    const int w = t >> 6, lane = t & 63;
    const int q = lane >> 4, n_lo = lane & 15;
    const int bk = blockIdx.x;        // 512 blocks, 128 rows each
    const int n0 = bk * 128;
    const int b  = n0 >> 10;
    const int sb = n0 & 1023;

    #pragma unroll
    for (int i = 0; i < 8; ++i) e2s[i * 128 + t] = e2f[i * 128 + t];

    // A fragments: bf16(-2 z) for this wave's 64 rows
    short8 af[4][2];
    #pragma unroll
    for (int rt = 0; rt < 4; ++rt) {
        const int s = sb + w * 64 + rt * 16 + n_lo;
        const float* zp = z + (size_t)b * 65536 + s;
        #pragma unroll
        for (int kh = 0; kh < 2; ++kh) {
            short8 fr;
            #pragma unroll
            for (int j = 0; j < 8; ++j) {
                int d = kh * 32 + q * 8 + j;
                fr[j] = (short)f2bf(-2.0f * zp[d * 1024]);
            }
            af[rt][kh] = fr;
        }
    }

    float b1[16], b2[16]; int i1[16];
    #pragma unroll
    for (int sl = 0; sl < 16; ++sl) { b1[sl] = 3.4e38f; b2[sl] = 3.4e38f; i1[sl] = 0; }

    // ---- phase 1: MFMA scan, top-2 per row ----
    for (int c = 0; c < 4; ++c) {
        __syncthreads();
        stage_chunk(Bs, emb, c, t);
        __syncthreads();
        #pragma unroll
        for (int t16 = 0; t16 < 8; ++t16) {
            short8 bf0[2], bf1[2];
            #pragma unroll
            for (int kh = 0; kh < 2; ++kh) {
                bf0[kh] = ((const short8*)Bs)[t16 * 256 + 0 * 128 + kh * 64 + lane];
                bf1[kh] = ((const short8*)Bs)[t16 * 256 + 1 * 128 + kh * 64 + lane];
            }
            const int cb0 = c * 256 + t16 * 32 + n_lo;
            const float e20 = e2s[cb0], e21 = e2s[cb0 + 16];
            #pragma unroll
            for (int rt = 0; rt < 4; ++rt) {
                f32x4 a0; a0[0] = e20; a0[1] = e20; a0[2] = e20; a0[3] = e20;
                a0 = __builtin_amdgcn_mfma_f32_16x16x32_bf16(af[rt][0], bf0[0], a0, 0, 0, 0);
                a0 = __builtin_amdgcn_mfma_f32_16x16x32_bf16(af[rt][1], bf0[1], a0, 0, 0, 0);
                f32x4 a1; a1[0] = e21; a1[1] = e21; a1[2] = e21; a1[3] = e21;
                a1 = __builtin_amdgcn_mfma_f32_16x16x32_bf16(af[rt][0], bf1[0], a1, 0, 0, 0);
                a1 = __builtin_amdgcn_mfma_f32_16x16x32_bf16(af[rt][1], bf1[1], a1, 0, 0, 0);
                #pragma unroll
                for (int reg = 0; reg < 4; ++reg) {
                    const int sl = rt * 4 + reg;
                    float s0 = a0[reg];
                    b2[sl] = __builtin_amdgcn_fmed3f(s0, b1[sl], b2[sl]);
                    bool lt0 = s0 < b1[sl];
                    i1[sl] = lt0 ? cb0 : i1[sl];
                    b1[sl] = lt0 ? s0 : b1[sl];
                    float s1 = a1[reg];
                    b2[sl] = __builtin_amdgcn_fmed3f(s1, b1[sl], b2[sl]);
                    bool lt1 = s1 < b1[sl];
                    i1[sl] = lt1 ? (cb0 + 16) : i1[sl];
                    b1[sl] = lt1 ? s1 : b1[sl];
                }
            }
        }
    }

    // merge across the 16 code-lanes of each quad
    #pragma unroll
    for (int m = 1; m < 16; m <<= 1) {
        #pragma unroll
        for (int sl = 0; sl < 16; ++sl) {
            float ob1 = __shfl_xor(b1[sl], m, 64);
            int   oi1 = __shfl_xor(i1[sl], m, 64);
            float ob2 = __shfl_xor(b2[sl], m, 64);
            float lose = fmaxf(b1[sl], ob1);
            b2[sl] = fminf(fminf(b2[sl], ob2), lose);
            bool take = (ob1 < b1[sl]) || (ob1 == b1[sl] && oi1 < i1[sl]);
            b1[sl] = take ? ob1 : b1[sl];
            i1[sl] = take ? oi1 : i1[sl];
        }
    }
    if (n_lo == 0) {
        #pragma unroll
        for (int rt = 0; rt < 4; ++rt) {
            #pragma unroll
            for (int reg = 0; reg < 4; ++reg) {
                int row = w * 64 + rt * 16 + q * 4 + reg;
                int sl = rt * 4 + reg;
                rowb1[row] = b1[sl];
                rowb2[row] = b2[sl];
                rowi1[row] = i1[sl];
            }
        }
    }
    __syncthreads();

    // ---- flag rows; index + hist for unflagged ----
    {
        const int r = t;
        const int nrow = n0 + r;
        int code = rowi1[r];
        int slot = -1;
        if (rowb2[r] < rowb1[r] + MARGIN) {
            unsigned p = atomicAdd(nflag, 1u);
            if (p < CAPF) {
                slot = (int)p;
                atomicExch(&rowcnt[p], ((unsigned)nrow) << 12);   // cnt=0
            }
        }
        rowslot[r] = slot;
        out[NELEM + nrow] = (float)code;       // rescue overwrites if flagged
        if (slot < 0) atomicAdd(&hist[code], 1u);
    }
    __syncthreads();

    // per-lane row info for phase 2
    float thr[16]; int slt[16];
    bool haveflag = false;
    #pragma unroll
    for (int rt = 0; rt < 4; ++rt) {
        #pragma unroll
        for (int reg = 0; reg < 4; ++reg) {
            int row = w * 64 + rt * 16 + q * 4 + reg;
            int sl = rt * 4 + reg;
            thr[sl] = rowb1[row] + MARGIN;
            slt[sl] = rowslot[row];
            haveflag |= (slt[sl] >= 0);
        }
    }
    const bool wactive = (__ballot(haveflag) != 0ULL);

    // ---- phase 2: re-scan (identical MFMA => identical scores), append candidates ----
    for (int c = 0; c < 4; ++c) {
        __syncthreads();
        stage_chunk(Bs, emb, c, t);
        __syncthreads();
        if (!wactive) continue;
        #pragma unroll
        for (int t16 = 0; t16 < 8; ++t16) {
            short8 bf0[2], bf1[2];
            #pragma unroll
            for (int kh = 0; kh < 2; ++kh) {
                bf0[kh] = ((const short8*)Bs)[t16 * 256 + 0 * 128 + kh * 64 + lane];
                bf1[kh] = ((const short8*)Bs)[t16 * 256 + 1 * 128 + kh * 64 + lane];
            }
            const int cb0 = c * 256 + t16 * 32 + n_lo;
            const float e20 = e2s[cb0], e21 = e2s[cb0 + 16];
            #pragma unroll
            for (int rt = 0; rt < 4; ++rt) {
                f32x4 a0; a0[0] = e20; a0[1] = e20; a0[2] = e20; a0[3] = e20;
                a0 = __builtin_amdgcn_mfma_f32_16x16x32_bf16(af[rt][0], bf0[0], a0, 0, 0, 0);
                a0 = __builtin_amdgcn_mfma_f32_16x16x32_bf16(af[rt][1], bf0[1], a0, 0, 0, 0);
                f32x4 a1; a1[0] = e21; a1[1] = e21; a1[2] = e21; a1[3] = e21;
                a1 = __builtin_amdgcn_mfma_f32_16x16x32_bf16(af[rt][0], bf1[0], a1, 0, 0, 0);
                a1 = __builtin_amdgcn_mfma_f32_16x16x32_bf16(af[rt][1], bf1[1], a1, 0, 0, 0);
                #pragma unroll
                for (int reg = 0; reg < 4; ++reg) {
                    const int sl = rt * 4 + reg;
                    if (slt[sl] >= 0) {
                        if (a0[reg] <= thr[sl]) {
                            unsigned pos = atomicAdd(&rowcnt[slt[sl]], 1u) & 4095u;
                            if (pos < MAXC) codes6[slt[sl] * MAXC + pos] = (unsigned short)cb0;
                        }
                        if (a1[reg] <= thr[sl]) {
                            unsigned pos = atomicAdd(&rowcnt[slt[sl]], 1u) & 4095u;
                            if (pos < MAXC) codes6[slt[sl] * MAXC + pos] = (unsigned short)(cb0 + 16);
                        }
                    }
                }
            }
        }
    }
    __syncthreads();

    // ---- epilogue: COALESCED z_q_st + loss. Lane owns row (w*64+lane). ----
    {
        const int myrow = w * 64 + lane;
        const int code = rowi1[myrow];
        const bool fl = rowslot[myrow] >= 0;
        const int scol = sb + myrow;           // spatial index of this row
        double lsum = 0.0;
        #pragma unroll
        for (int d4 = 0; d4 < 16; ++d4) {
            float4 e4 = *(const float4*)(emb + code * 64 + d4 * 4);  // gather, L1/L2-hot
            float es[4] = {e4.x, e4.y, e4.z, e4.w};
            #pragma unroll
            for (int j = 0; j < 4; ++j) {
                int d = d4 * 4 + j;
                size_t off = (size_t)b * 65536 + (size_t)d * 1024 + scol;
                float zv = z[off];                 // coalesced 256B
                out[off] = zv + (es[j] - zv);      // coalesced 256B
                double df = (double)es[j] - (double)zv;
                lsum = fma(df, df, lsum);
            }
        }
        if (fl) lsum = 0.0;                        // rescue adds flagged rows' loss
        #pragma unroll
        for (int off = 32; off > 0; off >>= 1)
            lsum += __shfl_down(lsum, off, 64);
        if (lane == 0) atomicAdd(loss_sum, lsum);
    }
}

// ---------------- rescue: thread per flagged row, exact R2 chain on candidates ----
__global__ __launch_bounds__(256, 1)
void vq_rescue(const float* __restrict__ z, const float* __restrict__ emb,
               const float* __restrict__ e2f, float* __restrict__ out,
               double* __restrict__ loss_sum, unsigned* __restrict__ hist,
               const unsigned* __restrict__ nflag,
               const unsigned* __restrict__ rowcnt,
               const unsigned short* __restrict__ codes6) {
    const int tid = blockIdx.x * 256 + threadIdx.x;
    unsigned nfr = *nflag;
    const int nf = (int)(nfr < CAPF ? nfr : CAPF);
    if (tid >= nf) return;
    const unsigned rc = rowcnt[tid];
    const int row = (int)(rc >> 12);
    const int cnt = (int)(rc & 4095u);
    const int b = row >> 10, s = row & 1023;

    float zr[64];
    #pragma unroll
    for (int k = 0; k < 64; ++k)
        zr[k] = z[(size_t)b * 65536 + (size_t)k * 1024 + s];

    double a = 0.0;
    #pragma unroll
    for (int k = 0; k < 64; ++k) a = fma((double)zr[k], (double)zr[k], a);
    const float zn = (float)a;        // fl32(fp64 ||z||^2), R2-proven

    float bv = 3.4e38f; int bi = 0x7fffffff;
    if (cnt <= MAXC) {
        for (int j = 0; j < cnt; ++j) {
            int c = (int)codes6[tid * MAXC + j];
            float m = 0.f;
            const float4* ep = (const float4*)(emb + c * 64);
            #pragma unroll
            for (int k4 = 0; k4 < 16; ++k4) {     // strict sequential k (R2-exact)
                float4 e4 = ep[k4];
                m = fmaf(zr[4*k4+0], e4.x, m); m = fmaf(zr[4*k4+1], e4.y, m);
                m = fmaf(zr[4*k4+2], e4.z, m); m = fmaf(zr[4*k4+3], e4.w, m);
            }
            float tt = zn + e2f[c];
            float d = tt - 2.0f * m;
            if (d < bv || (d == bv && c < bi)) { bv = d; bi = c; }
        }
    } else {                                      // overflow fallback (~never)
        for (int c = 0; c < VOCAB; ++c) {
            float m = 0.f;
            const float4* ep = (const float4*)(emb + c * 64);
            #pragma unroll
            for (int k4 = 0; k4 < 16; ++k4) {
                float4 e4 = ep[k4];
                m = fmaf(zr[4*k4+0], e4.x, m); m = fmaf(zr[4*k4+1], e4.y, m);
                m = fmaf(zr[4*k4+2], e4.z, m); m = fmaf(zr[4*k4+3], e4.w, m);
            }
            float tt = zn + e2f[c];
            float d = tt - 2.0f * m;
            if (d < bv) { bv = d; bi = c; }       // ascending c: strict < = first-occurrence
        }
    }

    out[NELEM + row] = (float)bi;
    atomicAdd(&hist[bi], 1u);
    double lsum = 0.0;
    #pragma unroll
    for (int k = 0; k < 64; ++k) {
        float e = emb[bi * 64 + k];
        size_t off = (size_t)b * 65536 + (size_t)k * 1024 + s;
        out[off] = zr[k] + (e - zr[k]);
        double df = (double)e - (double)zr[k];
        lsum = fma(df, df, lsum);
    }
    atomicAdd(loss_sum, lsum);
}

// ---------------- finalize ----------------
__global__ void vq_finalize_kernel(const unsigned* __restrict__ hist,
                                   const double* __restrict__ loss_sum,
                                   float* __restrict__ out) {
    __shared__ double red[256];
    int t = threadIdx.x;
    double ssum = 0.0;
    for (int i = t; i < VOCAB; i += 256) {
        double p = (double)hist[i] / (double)NROWS;
        ssum += p * log(p + 1e-10);
    }
    red[t] = ssum;
    __syncthreads();
    for (int off = 128; off > 0; off >>= 1) {
        if (t < off) red[t] += red[t + off];
        __syncthreads();
    }
    if (t == 0) {
        double qv = loss_sum[0] / (double)NELEM;
        out[NELEM + NROWS + 0] = (float)qv;
        out[NELEM + NROWS + 1] = (float)(qv * 0.25);
        out[NELEM + NROWS + 2] = (float)exp(-red[0]);
    }
}

extern "C" void kernel_launch(void* const* d_in, const int* in_sizes, int n_in,
                              void* d_out, int out_size, void* d_ws, size_t ws_size,
                              hipStream_t stream) {
    const float* z   = (const float*)d_in[0];   // (64,64,32,32) fp32
    const float* emb = (const float*)d_in[1];   // (1024,64) fp32
    float* out = (float*)d_out;

    float*          e2f    = (float*)d_ws;
    double*         loss   = (double*)((char*)d_ws + 4096);
    unsigned*       nfl    = (unsigned*)((char*)d_ws + 4104);
    unsigned*       hist   = (unsigned*)((char*)d_ws + 4112);
    unsigned*       rcnt   = (unsigned*)((char*)d_ws + 8208);
    unsigned short* codes6 = (unsigned short*)((char*)d_ws + 40976);

    // zero loss + nflag + pad + hist
    hipMemsetAsync((char*)d_ws + 4096, 0, 4112, stream);

    vq_prep<<<dim3(4), dim3(256), 0, stream>>>(emb, e2f);
    vq_filter<<<dim3(512), dim3(128), 0, stream>>>(z, emb, e2f, out, loss,
                                                   hist, nfl, rcnt, codes6);
    vq_rescue<<<dim3(CAPF / 256), dim3(256), 0, stream>>>(z, emb, e2f, out,
                                                          loss, hist, nfl,
                                                          rcnt, codes6);
    vq_finalize_kernel<<<dim3(1), dim3(256), 0, stream>>>(hist, loss, out);
}